// Round 5
// baseline (325.015 us; speedup 1.0000x reference)
//
#include <hip/hip_runtime.h>

typedef __attribute__((ext_vector_type(8))) short bfrag;   // 8 bf16 (4 VGPRs) MFMA operand
typedef __attribute__((ext_vector_type(4))) short s4;      // 4 bf16 (2 VGPRs) 16x16x16 operand
typedef __attribute__((ext_vector_type(4))) float f4;      // MFMA accumulator
typedef unsigned short u16;
typedef __attribute__((ext_vector_type(4))) unsigned short u16x4;

#define L2T 0.20762050593046f   // log2(10000)/64

__device__ inline u16 f2bf(float x) {
    unsigned u = __builtin_bit_cast(unsigned, x);
    u += 0x7FFFu + ((u >> 16) & 1u);   // round-to-nearest-even
    return (u16)(u >> 16);
}

__device__ inline void gload16(const u16* g, u16* l) {
    // async global->LDS, 16B/lane; LDS dst = wave-uniform base + lane*16
    __builtin_amdgcn_global_load_lds((const __attribute__((address_space(1))) u16*)g,
                                     (__attribute__((address_space(3))) u16*)l, 16, 0, 0);
}

// ---------------- fused prep: cast X/wq/wk/wv/wo -> bf16, concat biases ----------------
__global__ __launch_bounds__(256) void prep(const float* __restrict__ X,  const float* __restrict__ wq,
                                            const float* __restrict__ wk, const float* __restrict__ wv,
                                            const float* __restrict__ wo, const float* __restrict__ bq,
                                            const float* __restrict__ bk, const float* __restrict__ bv,
                                            u16* __restrict__ Xb, u16* __restrict__ Wqkv,
                                            u16* __restrict__ Wo_, float* __restrict__ biasqkv) {
    const int v = blockIdx.x * 256 + threadIdx.x;
    const float* src; u16* dst; int idx;
    if (v < 1048576)      { src = X;  dst = Xb;              idx = v; }
    else if (v < 2097152) { src = wq; dst = Wqkv;            idx = v - 1048576; }
    else if (v < 2359296) { src = wk; dst = Wqkv + 4194304;  idx = v - 2097152; }
    else if (v < 2621440) { src = wv; dst = Wqkv + 5242880;  idx = v - 2359296; }
    else if (v < 3670016) { src = wo; dst = Wo_;             idx = v - 2621440; }
    else {
        const int b = v - 3670016;   // 768 float4 = 3072 bias floats
        const float* s = (b < 512) ? (bq + b * 4) : (b < 640) ? (bk + (b - 512) * 4) : (bv + (b - 640) * 4);
        *(float4*)(biasqkv + b * 4) = *(const float4*)s;
        return;
    }
    float4 t = *(const float4*)(src + (size_t)idx * 4);
    u16x4 o;
    o.x = f2bf(t.x); o.y = f2bf(t.y); o.z = f2bf(t.z); o.w = f2bf(t.w);
    *(u16x4*)(dst + (size_t)idx * 4) = o;
}

// ---------------- fused QKV GEMM + bias + RoPE + repack ----------------
// C = Xb[2048][2048] * Wqkv[3072][2048]^T. 128x128 tiles, BK=32, 256 thr = 4 waves;
// wave w owns rows w*32..w*32+31 x all 128 cols (acc[2][8]) so RoPE partners
// (i, i+64) are acc[i][j] <-> acc[i][j+4] IN-LANE. tn: 0..15 Q head tn,
// 16..19 K head tn-16, 20..23 V kv-head tn-20 (written transposed to Vt).
__global__ __launch_bounds__(256) void gemm_qkv_rope(const u16* __restrict__ A, const u16* __restrict__ B,
                                                     const float* __restrict__ bias,
                                                     u16* __restrict__ Qr, u16* __restrict__ Kr,
                                                     u16* __restrict__ Vt) {
    const int K = 2048;
    __shared__ u16 As[128 * 32];
    __shared__ u16 Bs[128 * 32];
    const int tm = blockIdx.y, tn = blockIdx.x;
    const int tid = threadIdx.x;
    const int w = tid >> 6, lane = tid & 63, quad = lane >> 4, l16 = lane & 15;

    f4 acc[2][8];
#pragma unroll
    for (int i = 0; i < 2; i++)
#pragma unroll
        for (int j = 0; j < 8; j++) acc[i][j] = f4{0.f, 0.f, 0.f, 0.f};

    const int srow = w * 32 + (lane >> 2);
    const int scol = (lane & 3) * 8;
    const u16* aPtr = A + (size_t)(tm * 128 + srow) * K + scol;
    const u16* bPtr = B + (size_t)(tn * 128 + srow) * K + scol;
    u16* aLds0 = &As[(w * 32) * 32];
    u16* aLds1 = &As[(w * 32 + 16) * 32];
    u16* bLds0 = &Bs[(w * 32) * 32];
    u16* bLds1 = &Bs[(w * 32 + 16) * 32];
    const size_t rowskip = (size_t)16 * K;

    for (int k0 = 0; k0 < K; k0 += 32) {
        __syncthreads();
        gload16(aPtr,           aLds0);
        gload16(aPtr + rowskip, aLds1);
        gload16(bPtr,           bLds0);
        gload16(bPtr + rowskip, bLds1);
        aPtr += 32; bPtr += 32;
        __syncthreads();

        bfrag af[2], bf[8];
#pragma unroll
        for (int i = 0; i < 2; i++)
            af[i] = *(const bfrag*)(&As[(w * 32 + i * 16 + l16) * 32 + quad * 8]);
#pragma unroll
        for (int j = 0; j < 8; j++)
            bf[j] = *(const bfrag*)(&Bs[(j * 16 + l16) * 32 + quad * 8]);
#pragma unroll
        for (int i = 0; i < 2; i++)
#pragma unroll
            for (int j = 0; j < 8; j++)
                acc[i][j] = __builtin_amdgcn_mfma_f32_16x16x32_bf16(af[i], bf[j], acc[i][j], 0, 0, 0);
    }

    // ---- epilogue ----
    if (tn < 20) {   // Q or K: bias + RoPE + head-major write
        const int qk = (tn < 16);
        const int hd = qk ? tn : (tn - 16);
        u16* base = qk ? (Qr + (size_t)hd * 2048 * 128) : (Kr + (size_t)hd * 2048 * 128);
        float bia0[4], bia1[4], inv[4];
#pragma unroll
        for (int j = 0; j < 4; j++) {
            const int ip = j * 16 + l16;
            bia0[j] = bias[tn * 128 + ip];
            bia1[j] = bias[tn * 128 + ip + 64];
            inv[j] = exp2f(-(float)ip * L2T);
        }
#pragma unroll
        for (int i = 0; i < 2; i++) {
            const int s0 = tm * 128 + w * 32 + i * 16 + quad * 4;
#pragma unroll
            for (int r = 0; r < 4; r++) {
                const int s = s0 + r;
                const float fs = (float)s;
                u16* rowp = base + (size_t)s * 128;
#pragma unroll
                for (int j = 0; j < 4; j++) {
                    const int ip = j * 16 + l16;
                    float sn, cs;
                    __sincosf(fs * inv[j], &sn, &cs);
                    const float a0 = acc[i][j][r] + bia0[j];
                    const float a1 = acc[i][j + 4][r] + bia1[j];
                    rowp[ip]      = f2bf(a0 * cs - a1 * sn);
                    rowp[ip + 64] = f2bf(a1 * cs + a0 * sn);
                }
            }
        }
    } else {         // V: bias + transposed write to Vt[4][128][2048]
        const int kvh = tn - 20;
#pragma unroll
        for (int j = 0; j < 8; j++) {
            const int d = j * 16 + l16;
            const float bv = bias[tn * 128 + d];
            u16* base = Vt + ((size_t)(kvh * 128 + d)) * 2048;
#pragma unroll
            for (int i = 0; i < 2; i++) {
                const int s0 = tm * 128 + w * 32 + i * 16 + quad * 4;
                u16x4 o;
#pragma unroll
                for (int r = 0; r < 4; r++) o[r] = f2bf(acc[i][j][r] + bv);
                *(u16x4*)(base + s0) = o;
            }
        }
    }
}

// ---------------- GEMM: C[M][N] = A[M][K](bf16) * B[N][K]^T(bf16), fp32 out ----------------
// 128x128 tile, BK=32, 256 threads = 4 waves (2x2), m97 structure, global_load_lds staging.
__global__ __launch_bounds__(256) void gemm_bt(const u16* __restrict__ A, const u16* __restrict__ B,
                                               float* __restrict__ C, int M, int N, int K) {
    __shared__ u16 As[128 * 32];
    __shared__ u16 Bs[128 * 32];
    const int tm = blockIdx.y, tn = blockIdx.x;
    const int tid = threadIdx.x;
    const int w = tid >> 6, lane = tid & 63, quad = lane >> 4, l16 = lane & 15;
    const int wm = w >> 1, wn = w & 1;

    f4 acc[4][4];
#pragma unroll
    for (int i = 0; i < 4; i++)
#pragma unroll
        for (int j = 0; j < 4; j++) acc[i][j] = f4{0.f, 0.f, 0.f, 0.f};

    const int srow = w * 32 + (lane >> 2);
    const int scol = (lane & 3) * 8;
    const u16* aPtr = A + (size_t)(tm * 128 + srow) * K + scol;
    const u16* bPtr = B + (size_t)(tn * 128 + srow) * K + scol;
    u16* aLds0 = &As[(w * 32) * 32];
    u16* aLds1 = &As[(w * 32 + 16) * 32];
    u16* bLds0 = &Bs[(w * 32) * 32];
    u16* bLds1 = &Bs[(w * 32 + 16) * 32];
    const size_t rowskip = (size_t)16 * K;

    for (int k0 = 0; k0 < K; k0 += 32) {
        __syncthreads();
        gload16(aPtr,           aLds0);
        gload16(aPtr + rowskip, aLds1);
        gload16(bPtr,           bLds0);
        gload16(bPtr + rowskip, bLds1);
        aPtr += 32; bPtr += 32;
        __syncthreads();

        bfrag af[4], bf[4];
#pragma unroll
        for (int i = 0; i < 4; i++)
            af[i] = *(const bfrag*)(&As[(wm * 64 + i * 16 + l16) * 32 + quad * 8]);
#pragma unroll
        for (int j = 0; j < 4; j++)
            bf[j] = *(const bfrag*)(&Bs[(wn * 64 + j * 16 + l16) * 32 + quad * 8]);
#pragma unroll
        for (int i = 0; i < 4; i++)
#pragma unroll
            for (int j = 0; j < 4; j++)
                acc[i][j] = __builtin_amdgcn_mfma_f32_16x16x32_bf16(af[i], bf[j], acc[i][j], 0, 0, 0);
    }

#pragma unroll
    for (int i = 0; i < 4; i++) {
#pragma unroll
        for (int j = 0; j < 4; j++) {
            const int col = tn * 128 + wn * 64 + j * 16 + l16;
#pragma unroll
            for (int r = 0; r < 4; r++) {
                const int row = tm * 128 + wm * 64 + i * 16 + quad * 4 + r;
                C[(size_t)row * N + col] = acc[i][j][r];
            }
        }
    }
}

// ---------------- flash attention (causal): barrier-free, direct-from-L2 ----------------
// K/V per kv head = 512KB+512KB: L2-RESIDENT (4MB/XCD). Per guide lesson #7 (m169), LDS
// staging of L2-fit data is pure overhead -- rounds 0-4 were all bound by the serial
// stage->drain->barrier chain (all pipes <20% busy). This version: NO LDS, NO barriers.
// Each wave is fully independent: unit = (head h, 32-row q-group G, key-parity split sp),
// 2048 waves total, 8 waves/CU. K/V fragments are loaded straight from global (L2) with
// the de-swizzled forms of the verified LDS read mappings (stage XOR and read XOR cancel):
//   K bfrag: Kr[kv][kt*128 + nt*16 + l16][(quad+kb*4)*8 ..+7]
//   V s4:    Vt[kv][d = ct*16+l16][kt*128 + nt*16 + (quad>>1)*8 + (quad&1)*4 ..+3]
// QK -> mask -> softmax -> PV fused per 16-key slab nt: slab nt+1's 12 loads issue under
// slab nt's 24 MFMA + ~40 VALU (deep per-wave ILP; compiler emits counted vmcnt).
// Balance: block p covers roles {(p,0),(63-p,0),(31-p,1),(32+p,1)} = exactly 17 tiles per
// block; pairing-parity role swap (w0<->w1) makes co-resident SIMD sums ~{9,9,8,8} under
// either (2j,2j+1) or (j,j+32) within-XCD pairing. kv head pinned to XCD (bid&7) so each
// XCD touches ONE kv head's K/V (1MB, L2-resident).
// Key-split partials are additive (streaming softmax, no running max): unnormalized f32
// O-partials + row-sum partials per split; combine() sums, normalizes, casts.
// PV C/D layout: oacc[g][ct][r] = O[q = G*32+g*16+l16][d = ct*16+quad*4+r] (f4 walks d!).
__global__ __launch_bounds__(256, 2) void flash_attn(const u16* __restrict__ Qr, const u16* __restrict__ Kr,
                                                     const u16* __restrict__ Vt,
                                                     float* __restrict__ opA, float* __restrict__ opB,
                                                     float* __restrict__ psA, float* __restrict__ psB) {
    const int bid = blockIdx.x;
    const int x = bid & 7;            // XCD (round-robin dispatch)
    const int u = bid >> 3;           // 0..63 within-XCD sequence
    const int kv = x & 3;             // kv head pinned to an XCD pair -> L2 locality
    const int hq = u & 3;
    const int h = kv * 4 + hq;        // this block's q-head
    const int p = (u >> 2) | ((x >> 2) << 4);   // 0..31
    const int tid = threadIdx.x;
    const int w = tid >> 6, lane = tid & 63, quad = lane >> 4, l16 = lane & 15;

    // wave role -> (G, sp). Role multiset per block = {p,0},{63-p,0},{31-p,1},{32+p,1}
    // (tiles {ceil,ceil,floor,floor} summing to 17). Swap w0<->w1 on pairing parity so
    // two co-resident blocks' SIMD sums are ~{9,9,8,8} for both plausible pairings.
    const int par = (u ^ (u >> 5)) & 1;
    const int role = (par && w < 2) ? (1 - w) : w;
    const int G  = (role == 0) ? p : (role == 1) ? (63 - p) : (role == 2) ? (31 - p) : (32 + p);
    const int sp = role >> 1;         // key-tile parity split

    const u16* kbase = Kr + (size_t)kv * 2048 * 128;
    const u16* vbase = Vt + (size_t)kv * 128 * 2048;
    const float C = 0.08838834764831845f * 1.4426950408889634f;  // (1/sqrt(128))*log2(e)

    // Q fragments for both row-groups (B-operand layout: rows q=l16, k at quad*8)
    bfrag aq[2][4];
    const u16* qbase = Qr + ((size_t)(h * 2048 + G * 32 + l16)) * 128 + quad * 8;
#pragma unroll
    for (int kb = 0; kb < 4; kb++) {
        aq[0][kb] = *(const bfrag*)(qbase + kb * 32);
        aq[1][kb] = *(const bfrag*)(qbase + 16 * 128 + kb * 32);
    }

    f4 oacc[2][8];
#pragma unroll
    for (int g = 0; g < 2; g++)
#pragma unroll
        for (int ct = 0; ct < 8; ct++) oacc[g][ct] = f4{0.f, 0.f, 0.f, 0.f};
    float psum0 = 0.f, psum1 = 0.f;   // per-lane partial row-sums (q = l16 of each group)

    const int qg0 = G * 32 + l16;     // group-0 lane q row; group 1 = +16
    const int ktn = G / 4 + 1;        // causal 128-key tiles for rows [G*32, G*32+32)
    const int lastkt = ktn - 1;       // only this tile needs the causal mask

    for (int kt = sp; kt < ktn; kt += 2) {
        // per-tile lane base pointers (nt walks +16 keys = +2048 u16 for K, +16 u16 for V)
        const u16* kp = kbase + (size_t)(kt * 128 + l16) * 128 + quad * 8;
        const u16* vp = vbase + (size_t)l16 * 2048 + kt * 128 + (quad >> 1) * 8 + (quad & 1) * 4;
        const bool last = (kt == lastkt);

#pragma unroll
        for (int nt = 0; nt < 8; nt++) {
            // ---- QK for this 16-key slab: K frag read once feeds BOTH groups ----
            f4 c0 = f4{0.f, 0.f, 0.f, 0.f}, c1 = f4{0.f, 0.f, 0.f, 0.f};
#pragma unroll
            for (int kb = 0; kb < 4; kb++) {
                bfrag a = *(const bfrag*)(kp + (size_t)nt * 2048 + kb * 32);
                c0 = __builtin_amdgcn_mfma_f32_16x16x32_bf16(a, aq[0][kb], c0, 0, 0, 0);
                c1 = __builtin_amdgcn_mfma_f32_16x16x32_bf16(a, aq[1][kb], c1, 0, 0, 0);
            }
            if (last) {
                const int key = kt * 128 + nt * 16 + quad * 4;
#pragma unroll
                for (int r = 0; r < 4; r++) {
                    if (key + r > qg0)      c0[r] = -INFINITY;
                    if (key + r > qg0 + 16) c1[r] = -INFINITY;
                }
            }
            // ---- streaming softmax + in-lane P pack (16x16x16 A/B-operand layout) ----
            s4 p0, p1;
#pragma unroll
            for (int r = 0; r < 4; r++) {
                const float e0 = exp2f(fminf(c0[r] * C, 40.f));
                const float e1 = exp2f(fminf(c1[r] * C, 40.f));
                psum0 += e0; psum1 += e1;
                p0[r] = (short)f2bf(e0);
                p1[r] = (short)f2bf(e1);
            }
            // ---- PV for this slab: V^T frag read once feeds BOTH groups ----
#pragma unroll
            for (int ct = 0; ct < 8; ct++) {
                s4 a = *(const s4*)(vp + (size_t)(ct * 16) * 2048 + nt * 16);
                oacc[0][ct] = __builtin_amdgcn_mfma_f32_16x16x16bf16_1k(a, p0, oacc[0][ct], 0, 0, 0);
                oacc[1][ct] = __builtin_amdgcn_mfma_f32_16x16x16bf16_1k(a, p1, oacc[1][ct], 0, 0, 0);
            }
        }
    }

    // epilogue: per group, reduce psum over the 4 quads sharing q=l16, then write f32
    // partials: opart layout (f4 units) [h][qg16][ct][quad][l16]; each f4 holds d =
    // ct*16+quad*4 .. +3 at fixed q = qg16*16+l16. psum partial [h][q]. Zero-tile waves
    // (ktn<=sp) naturally write zeros (additive identity).
    float* opp = sp ? opB : opA;
    float* psp = sp ? psB : psA;
#pragma unroll
    for (int g = 0; g < 2; g++) {
        float s = g ? psum1 : psum0;
        s += __shfl_xor(s, 16, 64);
        s += __shfl_xor(s, 32, 64);
        if (quad == 0) psp[h * 2048 + G * 32 + g * 16 + l16] = s;
        const int qg16 = G * 2 + g;
#pragma unroll
        for (int ct = 0; ct < 8; ct++) {
            const size_t idx = ((((size_t)h * 128 + qg16) * 8 + ct) * 4 + quad) * 16 + l16;
            *(f4*)(opp + idx * 4) = oacc[g][ct];
        }
    }
}

// ---------------- combine: attnout = bf16( (opA+opB) / (psA+psB) ) ----------------
// 262144 threads; thread t = (h, qg16, ct, l16) gathers its row's 4 quads (4 coalesced f4
// loads per partial: consecutive l16 -> consecutive 16B units), one scalar denominator at
// q = qg16*16+l16, and stores 16 contiguous bf16 (32B) at attnout[q][h*128 + ct*16 ..+15].
// f4 component r maps to d = ct*16 + quad*4 + r (PV C/D layout: f4 walks d, NOT q).
__global__ __launch_bounds__(256) void combine(const float* __restrict__ opA, const float* __restrict__ opB,
                                               const float* __restrict__ psA, const float* __restrict__ psB,
                                               u16* __restrict__ attnout) {
    const size_t t = (size_t)blockIdx.x * 256 + threadIdx.x;   // 0 .. 262143
    const int l16 = (int)t & 15;
    const int ct = (int)(t >> 4) & 7;
    const int qg16 = (int)(t >> 7) & 127;
    const int h = (int)(t >> 14);
    const int q = qg16 * 16 + l16;
    // float offset of (h, qg16, ct, quad=0, l16): idx*4 with idx = (((h*128+qg16)*8+ct)*4+0)*16+l16
    const size_t base = ((((size_t)h * 128 + qg16) * 8 + ct) * 256) + (size_t)l16 * 4;

    const float inv = 1.0f / (psA[h * 2048 + q] + psB[h * 2048 + q]);

    u16x4 ov[4];
#pragma unroll
    for (int quad = 0; quad < 4; quad++) {
        const f4 oa = *(const f4*)(opA + base + quad * 64);
        const f4 ob = *(const f4*)(opB + base + quad * 64);
#pragma unroll
        for (int r = 0; r < 4; r++) ov[quad][r] = f2bf((oa[r] + ob[r]) * inv);
    }
    u16* dst = attnout + (size_t)q * 2048 + h * 128 + ct * 16;
    *(u16x4*)(dst)      = ov[0];
    *(u16x4*)(dst + 4)  = ov[1];
    *(u16x4*)(dst + 8)  = ov[2];
    *(u16x4*)(dst + 12) = ov[3];
}

// ---------------- launch ----------------
extern "C" void kernel_launch(void* const* d_in, const int* in_sizes, int n_in,
                              void* d_out, int out_size, void* d_ws, size_t ws_size,
                              hipStream_t stream) {
    const float* X  = (const float*)d_in[0];
    const float* wq = (const float*)d_in[3];
    const float* bq = (const float*)d_in[4];
    const float* wk = (const float*)d_in[5];
    const float* bk = (const float*)d_in[6];
    const float* wv = (const float*)d_in[7];
    const float* bv = (const float*)d_in[8];
    const float* wo = (const float*)d_in[9];

    char* ws = (char*)d_ws;
    u16*   Xb      = (u16*)(ws);                         // 8 MB  (dead after gemm_qkv_rope)
    u16*   Wqkv    = (u16*)(ws + 8388608);               // 12 MB (dead after gemm_qkv_rope)
    u16*   Wo      = (u16*)(ws + 20971520);              // 8 MB  (live until gemm_bt)
    float* biasqkv = (float*)(ws + 29360128);            // 12 KB (ends 29372416)
    u16*   Qr      = (u16*)(ws + 54538240);              // 8 MB   [16][2048][128]
    u16*   Kr      = (u16*)(ws + 62926848);              // 2 MB   [4][2048][128]
    u16*   attnout = (u16*)(ws + 67121152);              // 8 MB   [2048][2048]
    u16*   Vt      = (u16*)(ws + 75509760);              // 2 MB   [4][128][2048]
    // flash partials reuse dead/gap regions (no footprint growth past 79.7 MB):
    float* opA     = (float*)(ws);                       // 16 MB over Xb+Wqkv (dead)
    float* opB     = (float*)(ws + 29372416);            // 16 MB in the 29.37..54.5 MB gap
    float* psA     = (float*)(ws + 46149632);            // 128 KB
    float* psB     = (float*)(ws + 46280704);            // 128 KB (ends 46.4 MB < 54.5 MB)

    prep<<<14339, 256, 0, stream>>>(X, wq, wk, wv, wo, bq, bk, bv, Xb, Wqkv, Wo, biasqkv);
    gemm_qkv_rope<<<dim3(24, 16), 256, 0, stream>>>(Xb, Wqkv, biasqkv, Qr, Kr, Vt);
    flash_attn<<<512, 256, 0, stream>>>(Qr, Kr, Vt, opA, opB, psA, psB);
    combine<<<1024, 256, 0, stream>>>(opA, opB, psA, psB, attnout);
    gemm_bt<<<dim3(16, 16), 256, 0, stream>>>(attnout, Wo, (float*)d_out, 2048, 2048, 2048);
}

// Round 6
// 281.204 us; speedup vs baseline: 1.1558x; 1.1558x over previous
//
#include <hip/hip_runtime.h>

typedef __attribute__((ext_vector_type(8))) short bfrag;   // 8 bf16 (4 VGPRs) MFMA operand
typedef __attribute__((ext_vector_type(4))) short s4;      // 4 bf16 (2 VGPRs) 16x16x16 operand
typedef __attribute__((ext_vector_type(4))) float f4;      // MFMA accumulator
typedef unsigned short u16;
typedef __attribute__((ext_vector_type(4))) unsigned short u16x4;

#define L2T 0.20762050593046f   // log2(10000)/64

__device__ inline u16 f2bf(float x) {
    unsigned u = __builtin_bit_cast(unsigned, x);
    u += 0x7FFFu + ((u >> 16) & 1u);   // round-to-nearest-even
    return (u16)(u >> 16);
}

__device__ inline void gload16(const u16* g, u16* l) {
    // async global->LDS, 16B/lane; LDS dst = wave-uniform base + lane*16
    __builtin_amdgcn_global_load_lds((const __attribute__((address_space(1))) u16*)g,
                                     (__attribute__((address_space(3))) u16*)l, 16, 0, 0);
}

// ---------------- fused prep: cast X/wq/wk/wv/wo -> bf16, concat biases ----------------
__global__ __launch_bounds__(256) void prep(const float* __restrict__ X,  const float* __restrict__ wq,
                                            const float* __restrict__ wk, const float* __restrict__ wv,
                                            const float* __restrict__ wo, const float* __restrict__ bq,
                                            const float* __restrict__ bk, const float* __restrict__ bv,
                                            u16* __restrict__ Xb, u16* __restrict__ Wqkv,
                                            u16* __restrict__ Wo_, float* __restrict__ biasqkv) {
    const int v = blockIdx.x * 256 + threadIdx.x;
    const float* src; u16* dst; int idx;
    if (v < 1048576)      { src = X;  dst = Xb;              idx = v; }
    else if (v < 2097152) { src = wq; dst = Wqkv;            idx = v - 1048576; }
    else if (v < 2359296) { src = wk; dst = Wqkv + 4194304;  idx = v - 2097152; }
    else if (v < 2621440) { src = wv; dst = Wqkv + 5242880;  idx = v - 2359296; }
    else if (v < 3670016) { src = wo; dst = Wo_;             idx = v - 2621440; }
    else {
        const int b = v - 3670016;   // 768 float4 = 3072 bias floats
        const float* s = (b < 512) ? (bq + b * 4) : (b < 640) ? (bk + (b - 512) * 4) : (bv + (b - 640) * 4);
        *(float4*)(biasqkv + b * 4) = *(const float4*)s;
        return;
    }
    float4 t = *(const float4*)(src + (size_t)idx * 4);
    u16x4 o;
    o.x = f2bf(t.x); o.y = f2bf(t.y); o.z = f2bf(t.z); o.w = f2bf(t.w);
    *(u16x4*)(dst + (size_t)idx * 4) = o;
}

// ---------------- fused QKV GEMM + bias + RoPE + repack ----------------
// C = Xb[2048][2048] * Wqkv[3072][2048]^T. 128x128 tiles, BK=32, 256 thr = 4 waves;
// wave w owns rows w*32..w*32+31 x all 128 cols (acc[2][8]) so RoPE partners
// (i, i+64) are acc[i][j] <-> acc[i][j+4] IN-LANE. tn: 0..15 Q head tn,
// 16..19 K head tn-16, 20..23 V kv-head tn-20 (written transposed to Vt).
// T3 minimum 2-phase dbuf: at ~1 block/CU (384 blocks) there is no co-resident partner
// block to hide the per-K-step stage drain, so stage(t+1) is issued BEFORE compute(t)
// and the trailing vmcnt(0)+barrier only pays the residual latency.
__global__ __launch_bounds__(256) void gemm_qkv_rope(const u16* __restrict__ A, const u16* __restrict__ B,
                                                     const float* __restrict__ bias,
                                                     u16* __restrict__ Qr, u16* __restrict__ Kr,
                                                     u16* __restrict__ Vt) {
    const int K = 2048;
    __shared__ u16 As[2][128 * 32];
    __shared__ u16 Bs[2][128 * 32];
    const int tm = blockIdx.y, tn = blockIdx.x;
    const int tid = threadIdx.x;
    const int w = tid >> 6, lane = tid & 63, quad = lane >> 4, l16 = lane & 15;

    f4 acc[2][8];
#pragma unroll
    for (int i = 0; i < 2; i++)
#pragma unroll
        for (int j = 0; j < 8; j++) acc[i][j] = f4{0.f, 0.f, 0.f, 0.f};

    const int srow = w * 32 + (lane >> 2);
    const int scol = (lane & 3) * 8;
    const u16* aPtr = A + (size_t)(tm * 128 + srow) * K + scol;
    const u16* bPtr = B + (size_t)(tn * 128 + srow) * K + scol;
    const size_t rowskip = (size_t)16 * K;

    auto stage = [&](int buf, int kk) {
        gload16(aPtr + kk,           &As[buf][(w * 32) * 32]);
        gload16(aPtr + kk + rowskip, &As[buf][(w * 32 + 16) * 32]);
        gload16(bPtr + kk,           &Bs[buf][(w * 32) * 32]);
        gload16(bPtr + kk + rowskip, &Bs[buf][(w * 32 + 16) * 32]);
    };

    stage(0, 0);
    asm volatile("s_waitcnt vmcnt(0)" ::: "memory");
    __builtin_amdgcn_s_barrier();
    asm volatile("" ::: "memory");

    for (int k0 = 0; k0 < K; k0 += 32) {
        const int cur = (k0 >> 5) & 1;
        const bool pf = (k0 + 32 < K);
        if (pf) stage(cur ^ 1, k0 + 32);   // issue next tile's loads before compute

        bfrag af[2], bf[8];
#pragma unroll
        for (int i = 0; i < 2; i++)
            af[i] = *(const bfrag*)(&As[cur][(w * 32 + i * 16 + l16) * 32 + quad * 8]);
#pragma unroll
        for (int j = 0; j < 8; j++)
            bf[j] = *(const bfrag*)(&Bs[cur][(j * 16 + l16) * 32 + quad * 8]);
#pragma unroll
        for (int i = 0; i < 2; i++)
#pragma unroll
            for (int j = 0; j < 8; j++)
                acc[i][j] = __builtin_amdgcn_mfma_f32_16x16x32_bf16(af[i], bf[j], acc[i][j], 0, 0, 0);

        if (pf) {
            asm volatile("s_waitcnt vmcnt(0)" ::: "memory");   // next tile landed
            __builtin_amdgcn_s_barrier();
            asm volatile("" ::: "memory");
        }
    }

    // ---- epilogue ----
    if (tn < 20) {   // Q or K: bias + RoPE + head-major write
        const int qk = (tn < 16);
        const int hd = qk ? tn : (tn - 16);
        u16* base = qk ? (Qr + (size_t)hd * 2048 * 128) : (Kr + (size_t)hd * 2048 * 128);
        float bia0[4], bia1[4], inv[4];
#pragma unroll
        for (int j = 0; j < 4; j++) {
            const int ip = j * 16 + l16;
            bia0[j] = bias[tn * 128 + ip];
            bia1[j] = bias[tn * 128 + ip + 64];
            inv[j] = exp2f(-(float)ip * L2T);
        }
#pragma unroll
        for (int i = 0; i < 2; i++) {
            const int s0 = tm * 128 + w * 32 + i * 16 + quad * 4;
#pragma unroll
            for (int r = 0; r < 4; r++) {
                const int s = s0 + r;
                const float fs = (float)s;
                u16* rowp = base + (size_t)s * 128;
#pragma unroll
                for (int j = 0; j < 4; j++) {
                    const int ip = j * 16 + l16;
                    float sn, cs;
                    __sincosf(fs * inv[j], &sn, &cs);
                    const float a0 = acc[i][j][r] + bia0[j];
                    const float a1 = acc[i][j + 4][r] + bia1[j];
                    rowp[ip]      = f2bf(a0 * cs - a1 * sn);
                    rowp[ip + 64] = f2bf(a1 * cs + a0 * sn);
                }
            }
        }
    } else {         // V: bias + transposed write to Vt[4][128][2048]
        const int kvh = tn - 20;
#pragma unroll
        for (int j = 0; j < 8; j++) {
            const int d = j * 16 + l16;
            const float bv = bias[tn * 128 + d];
            u16* base = Vt + ((size_t)(kvh * 128 + d)) * 2048;
#pragma unroll
            for (int i = 0; i < 2; i++) {
                const int s0 = tm * 128 + w * 32 + i * 16 + quad * 4;
                u16x4 o;
#pragma unroll
                for (int r = 0; r < 4; r++) o[r] = f2bf(acc[i][j][r] + bv);
                *(u16x4*)(base + s0) = o;
            }
        }
    }
}

// ---------------- GEMM: C[M][N] = A[M][K](bf16) * B[N][K]^T(bf16), fp32 out ----------------
// 128x128 tile, BK=32, 256 threads = 4 waves (2x2), m97 structure + T3 minimum 2-phase
// dbuf (see gemm_qkv_rope comment: at 1 block/CU the stage drain is otherwise exposed).
__global__ __launch_bounds__(256) void gemm_bt(const u16* __restrict__ A, const u16* __restrict__ B,
                                               float* __restrict__ C, int M, int N, int K) {
    __shared__ u16 As[2][128 * 32];
    __shared__ u16 Bs[2][128 * 32];
    const int tm = blockIdx.y, tn = blockIdx.x;
    const int tid = threadIdx.x;
    const int w = tid >> 6, lane = tid & 63, quad = lane >> 4, l16 = lane & 15;
    const int wm = w >> 1, wn = w & 1;

    f4 acc[4][4];
#pragma unroll
    for (int i = 0; i < 4; i++)
#pragma unroll
        for (int j = 0; j < 4; j++) acc[i][j] = f4{0.f, 0.f, 0.f, 0.f};

    const int srow = w * 32 + (lane >> 2);
    const int scol = (lane & 3) * 8;
    const u16* aPtr = A + (size_t)(tm * 128 + srow) * K + scol;
    const u16* bPtr = B + (size_t)(tn * 128 + srow) * K + scol;
    const size_t rowskip = (size_t)16 * K;

    auto stage = [&](int buf, int kk) {
        gload16(aPtr + kk,           &As[buf][(w * 32) * 32]);
        gload16(aPtr + kk + rowskip, &As[buf][(w * 32 + 16) * 32]);
        gload16(bPtr + kk,           &Bs[buf][(w * 32) * 32]);
        gload16(bPtr + kk + rowskip, &Bs[buf][(w * 32 + 16) * 32]);
    };

    stage(0, 0);
    asm volatile("s_waitcnt vmcnt(0)" ::: "memory");
    __builtin_amdgcn_s_barrier();
    asm volatile("" ::: "memory");

    for (int k0 = 0; k0 < K; k0 += 32) {
        const int cur = (k0 >> 5) & 1;
        const bool pf = (k0 + 32 < K);
        if (pf) stage(cur ^ 1, k0 + 32);   // issue next tile's loads before compute

        bfrag af[4], bf[4];
#pragma unroll
        for (int i = 0; i < 4; i++)
            af[i] = *(const bfrag*)(&As[cur][(wm * 64 + i * 16 + l16) * 32 + quad * 8]);
#pragma unroll
        for (int j = 0; j < 4; j++)
            bf[j] = *(const bfrag*)(&Bs[cur][(wn * 64 + j * 16 + l16) * 32 + quad * 8]);
#pragma unroll
        for (int i = 0; i < 4; i++)
#pragma unroll
            for (int j = 0; j < 4; j++)
                acc[i][j] = __builtin_amdgcn_mfma_f32_16x16x32_bf16(af[i], bf[j], acc[i][j], 0, 0, 0);

        if (pf) {
            asm volatile("s_waitcnt vmcnt(0)" ::: "memory");   // next tile landed
            __builtin_amdgcn_s_barrier();
            asm volatile("" ::: "memory");
        }
    }

#pragma unroll
    for (int i = 0; i < 4; i++) {
#pragma unroll
        for (int j = 0; j < 4; j++) {
            const int col = tn * 128 + wn * 64 + j * 16 + l16;
#pragma unroll
            for (int r = 0; r < 4; r++) {
                const int row = tm * 128 + wm * 64 + i * 16 + quad * 4 + r;
                C[(size_t)row * N + col] = acc[i][j][r];
            }
        }
    }
}

// ---------------- flash attention (causal), S^T formulation, 128-key tiles ----------------
// [round-0 kernel, measured 64.1 us -- best of 6 variants; rounds 1-5 all regressed]
// 512 blocks x 256 threads = 4 waves. Block = (kv head, 16-row q-group g); wave w = q-head
// kv*4+w on the same 16 rows (GQA-shared staging). S^T via swapped-operand 16x16x32 MFMA:
// D[key][q] -> lane holds P[q=l16][key=quad*4+r], which IS the 16x16x16 MFMA operand layout,
// so PV runs as mfma_f32_16x16x16bf16_1k with NO P LDS round-trip and no in-loop shuffles.
// O accumulated as O[q=l16][d=ct*16+quad*4+r] (C-layout of A=V^T, B=P). Streaming softmax.
__global__ __launch_bounds__(256) void flash_attn(const u16* __restrict__ Qr, const u16* __restrict__ Kr,
                                                  const u16* __restrict__ Vt, u16* __restrict__ attnout) {
    const int bid = blockIdx.x;
    const int kv = bid & 3;
    const int gy = bid >> 2;          // 0..127
    const int g = ((gy & 1) << 6) | ((gy & 2) << 4) | ((gy & 4) << 2) | (gy & 8) |
                  ((gy & 16) >> 2) | ((gy & 32) >> 4) | ((gy & 64) >> 6);   // bitrev7
    const int tid = threadIdx.x;
    const int w = tid >> 6, lane = tid & 63, quad = lane >> 4, l16 = lane & 15;
    const int h = kv * 4 + w;         // wave's q-head

    __shared__ u16 ks[128 * 128];     // K tile [128 keys][128 d], swizzled 16B chunks
    __shared__ u16 vt[128 * 128];     // V^T tile [128 d][128 keys], swizzled 16B chunks

    // Q fragments (B-operand layout: rows q=l16, k at quad*8)
    bfrag aq[4];
    const u16* qbase = Qr + ((size_t)(h * 2048 + g * 16 + l16)) * 128 + quad * 8;
#pragma unroll
    for (int kb = 0; kb < 4; kb++) aq[kb] = *(const bfrag*)(qbase + kb * 32);

    f4 oacc[8];
#pragma unroll
    for (int ct = 0; ct < 8; ct++) oacc[ct] = f4{0.f, 0.f, 0.f, 0.f};
    float psum = 0.f;                 // per-lane partial row-sum for q = l16

    const int qg = g * 16 + l16;      // this lane's global q row
    const int ktn = g / 8 + 1;        // 128-key tiles for rows [g*16, g*16+16)
    const float C = 0.08838834764831845f * 1.4426950408889634f;  // (1/sqrt(128))*log2(e)
    const u16* kbase = Kr + (size_t)kv * 2048 * 128;
    const u16* vbase = Vt + (size_t)kv * 128 * 2048;

    for (int kt = 0; kt < ktn; kt++) {
        __syncthreads();
        // stage K [128][128]: 2048 chunks of 16B, 8 per thread
#pragma unroll
        for (int i = 0; i < 8; i++) {
            const int ci = (w * 8 + i) * 64 + lane;
            const int r = ci >> 4, c = (ci & 15) ^ (r & 15);
            gload16(kbase + (size_t)(kt * 128 + r) * 128 + c * 8, &ks[(w * 8 + i) * 512]);
        }
        // stage V^T [128 d][128 keys]: 2048 chunks
#pragma unroll
        for (int i = 0; i < 8; i++) {
            const int ci = (w * 8 + i) * 64 + lane;
            const int r = ci >> 4, c = (ci & 15) ^ (r & 15);
            gload16(vbase + (size_t)r * 2048 + kt * 128 + c * 8, &vt[(w * 8 + i) * 512]);
        }
        __syncthreads();

        // S^T: D[key][q] over 128 keys; A = K-frag (rows key), B = aq
        f4 sc[8];
#pragma unroll
        for (int nt = 0; nt < 8; nt++) {
            f4 c = f4{0.f, 0.f, 0.f, 0.f};
#pragma unroll
            for (int kb = 0; kb < 4; kb++) {
                bfrag a = *(const bfrag*)(&ks[((nt * 16 + l16) * 16 + ((quad + kb * 4) ^ l16)) * 8]);
                c = __builtin_amdgcn_mfma_f32_16x16x32_bf16(a, aq[kb], c, 0, 0, 0);
            }
            sc[nt] = c;
        }

        if (kt == ktn - 1) {          // only the last tile needs causal masking
#pragma unroll
            for (int nt = 0; nt < 8; nt++) {
                const int key = kt * 128 + nt * 16 + quad * 4;
#pragma unroll
                for (int r = 0; r < 4; r++)
                    if (key + r > qg) sc[nt][r] = -INFINITY;
            }
        }

        // streaming softmax + in-lane P pack (A/B-operand layout for 16x16x16)
        s4 pa[8];
#pragma unroll
        for (int nt = 0; nt < 8; nt++) {
#pragma unroll
            for (int r = 0; r < 4; r++) {
                const float p = exp2f(fminf(sc[nt][r] * C, 40.f));
                psum += p;
                pa[nt][r] = (short)f2bf(p);
            }
        }

        // O[q][d] += P*V via 16x16x16: A = V^T frag (rows d), B = P
#pragma unroll
        for (int nt = 0; nt < 8; nt++) {
#pragma unroll
            for (int ct = 0; ct < 8; ct++) {
                const int d = ct * 16 + l16;
                s4 a = *(const s4*)(&vt[(d * 16 + ((nt * 2 + (quad >> 1)) ^ l16)) * 8 + (quad & 1) * 4]);
                oacc[ct] = __builtin_amdgcn_mfma_f32_16x16x16bf16_1k(a, pa[nt], oacc[ct], 0, 0, 0);
            }
        }
    }

    // epilogue: reduce psum over the 4 quads sharing q=l16, normalize, vector-store
    float s = psum;
    s += __shfl_xor(s, 16, 64);
    s += __shfl_xor(s, 32, 64);
    const float inv_l = 1.0f / s;
    u16* orow = attnout + (size_t)qg * 2048 + h * 128;
#pragma unroll
    for (int ct = 0; ct < 8; ct++) {
        u16x4 o;
#pragma unroll
        for (int r = 0; r < 4; r++) o[r] = f2bf(oacc[ct][r] * inv_l);
        *(u16x4*)(orow + ct * 16 + quad * 4) = o;
    }
}

// ---------------- launch ----------------
extern "C" void kernel_launch(void* const* d_in, const int* in_sizes, int n_in,
                              void* d_out, int out_size, void* d_ws, size_t ws_size,
                              hipStream_t stream) {
    const float* X  = (const float*)d_in[0];
    const float* wq = (const float*)d_in[3];
    const float* bq = (const float*)d_in[4];
    const float* wk = (const float*)d_in[5];
    const float* bk = (const float*)d_in[6];
    const float* wv = (const float*)d_in[7];
    const float* bv = (const float*)d_in[8];
    const float* wo = (const float*)d_in[9];

    char* ws = (char*)d_ws;
    u16*   Xb      = (u16*)(ws);                         // 8 MB
    u16*   Wqkv    = (u16*)(ws + 8388608);               // 12 MB  [3072][2048]
    u16*   Wo      = (u16*)(ws + 20971520);              // 8 MB
    float* biasqkv = (float*)(ws + 29360128);            // 12 KB
    u16*   Qr      = (u16*)(ws + 54538240);              // 8 MB   [16][2048][128]
    u16*   Kr      = (u16*)(ws + 62926848);              // 2 MB   [4][2048][128]
    u16*   attnout = (u16*)(ws + 67121152);              // 8 MB   [2048][2048]
    u16*   Vt      = (u16*)(ws + 75509760);              // 2 MB   [4][128][2048]

    prep<<<14339, 256, 0, stream>>>(X, wq, wk, wv, wo, bq, bk, bv, Xb, Wqkv, Wo, biasqkv);
    gemm_qkv_rope<<<dim3(24, 16), 256, 0, stream>>>(Xb, Wqkv, biasqkv, Qr, Kr, Vt);
    flash_attn<<<512, 256, 0, stream>>>(Qr, Kr, Vt, attnout);
    gemm_bt<<<dim3(16, 16), 256, 0, stream>>>(attnout, Wo, (float*)d_out, 2048, 2048, 2048);
}

// Round 7
// 269.497 us; speedup vs baseline: 1.2060x; 1.0434x over previous
//
#include <hip/hip_runtime.h>

typedef __attribute__((ext_vector_type(8))) short bfrag;   // 8 bf16 (4 VGPRs) MFMA operand
typedef __attribute__((ext_vector_type(4))) short s4;      // 4 bf16 (2 VGPRs) 16x16x16 operand
typedef __attribute__((ext_vector_type(4))) float f4;      // MFMA accumulator
typedef unsigned short u16;
typedef __attribute__((ext_vector_type(4))) unsigned short u16x4;

#define L2T 0.20762050593046f   // log2(10000)/64

__device__ inline u16 f2bf(float x) {
    unsigned u = __builtin_bit_cast(unsigned, x);
    u += 0x7FFFu + ((u >> 16) & 1u);   // round-to-nearest-even
    return (u16)(u >> 16);
}

__device__ inline void gload16(const u16* g, u16* l) {
    // async global->LDS, 16B/lane; LDS dst = wave-uniform base + lane*16
    __builtin_amdgcn_global_load_lds((const __attribute__((address_space(1))) u16*)g,
                                     (__attribute__((address_space(3))) u16*)l, 16, 0, 0);
}

// ---------------- fused prep: cast X/wq/wk/wv/wo -> bf16, concat biases ----------------
__global__ __launch_bounds__(256) void prep(const float* __restrict__ X,  const float* __restrict__ wq,
                                            const float* __restrict__ wk, const float* __restrict__ wv,
                                            const float* __restrict__ wo, const float* __restrict__ bq,
                                            const float* __restrict__ bk, const float* __restrict__ bv,
                                            u16* __restrict__ Xb, u16* __restrict__ Wqkv,
                                            u16* __restrict__ Wo_, float* __restrict__ biasqkv) {
    const int v = blockIdx.x * 256 + threadIdx.x;
    const float* src; u16* dst; int idx;
    if (v < 1048576)      { src = X;  dst = Xb;              idx = v; }
    else if (v < 2097152) { src = wq; dst = Wqkv;            idx = v - 1048576; }
    else if (v < 2359296) { src = wk; dst = Wqkv + 4194304;  idx = v - 2097152; }
    else if (v < 2621440) { src = wv; dst = Wqkv + 5242880;  idx = v - 2359296; }
    else if (v < 3670016) { src = wo; dst = Wo_;             idx = v - 2621440; }
    else {
        const int b = v - 3670016;   // 768 float4 = 3072 bias floats
        const float* s = (b < 512) ? (bq + b * 4) : (b < 640) ? (bk + (b - 512) * 4) : (bv + (b - 640) * 4);
        *(float4*)(biasqkv + b * 4) = *(const float4*)s;
        return;
    }
    float4 t = *(const float4*)(src + (size_t)idx * 4);
    u16x4 o;
    o.x = f2bf(t.x); o.y = f2bf(t.y); o.z = f2bf(t.z); o.w = f2bf(t.w);
    *(u16x4*)(dst + (size_t)idx * 4) = o;
}

// ---------------- fused QKV GEMM + bias + RoPE + repack ----------------
// C = Xb[2048][2048] * Wqkv[3072][2048]^T. 128x128 tiles, BK=32, 256 thr = 4 waves;
// wave w owns rows w*32..w*32+31 x all 128 cols (acc[2][8]) so RoPE partners
// (i, i+64) are acc[i][j] <-> acc[i][j+4] IN-LANE. tn: 0..15 Q head tn,
// 16..19 K head tn-16, 20..23 V kv-head tn-20 (written transposed to Vt).
// DEPTH-3 COUNTED-VMCNT PIPELINE (T3/T4): 4 LDS buffers; iter t issues stage(t+3) and
// waits vmcnt(8) (tile t+1 landed, t+2/t+3 stay in flight across the barrier). Round-6's
// 2-phase version still drained vmcnt(0) per iter -- the anti-pattern; at 1 block/CU that
// exposed a full memory round-trip per K-step (MfmaUtil 9.7%). Buffer (t+3)%4=(t-1)%4 was
// last READ at iter t-1, before the end-of-(t-1) barrier -> overwrite is race-free.
__global__ __launch_bounds__(256) void gemm_qkv_rope(const u16* __restrict__ A, const u16* __restrict__ B,
                                                     const float* __restrict__ bias,
                                                     u16* __restrict__ Qr, u16* __restrict__ Kr,
                                                     u16* __restrict__ Vt) {
    const int K = 2048;
    const int NT = 64;                 // K/32
    __shared__ u16 As[4][128 * 32];
    __shared__ u16 Bs[4][128 * 32];
    const int tm = blockIdx.y, tn = blockIdx.x;
    const int tid = threadIdx.x;
    const int w = tid >> 6, lane = tid & 63, quad = lane >> 4, l16 = lane & 15;

    f4 acc[2][8];
#pragma unroll
    for (int i = 0; i < 2; i++)
#pragma unroll
        for (int j = 0; j < 8; j++) acc[i][j] = f4{0.f, 0.f, 0.f, 0.f};

    const int srow = w * 32 + (lane >> 2);
    const int scol = (lane & 3) * 8;
    const u16* aPtr = A + (size_t)(tm * 128 + srow) * K + scol;
    const u16* bPtr = B + (size_t)(tn * 128 + srow) * K + scol;
    const size_t rowskip = (size_t)16 * K;

    auto stage = [&](int buf, int kk) {
        gload16(aPtr + kk,           &As[buf][(w * 32) * 32]);
        gload16(aPtr + kk + rowskip, &As[buf][(w * 32 + 16) * 32]);
        gload16(bPtr + kk,           &Bs[buf][(w * 32) * 32]);
        gload16(bPtr + kk + rowskip, &Bs[buf][(w * 32 + 16) * 32]);
    };

    stage(0, 0); stage(1, 32); stage(2, 64);
    asm volatile("s_waitcnt vmcnt(8)" ::: "memory");   // tile 0 landed; 1,2 in flight
    __builtin_amdgcn_s_barrier();
    asm volatile("" ::: "memory");

    for (int t = 0; t < NT; t++) {
        const int cur = t & 3;
        if (t + 3 < NT) stage((t + 3) & 3, (t + 3) * 32);

        bfrag af[2], bf[8];
#pragma unroll
        for (int i = 0; i < 2; i++)
            af[i] = *(const bfrag*)(&As[cur][(w * 32 + i * 16 + l16) * 32 + quad * 8]);
#pragma unroll
        for (int j = 0; j < 8; j++)
            bf[j] = *(const bfrag*)(&Bs[cur][(j * 16 + l16) * 32 + quad * 8]);
#pragma unroll
        for (int i = 0; i < 2; i++)
#pragma unroll
            for (int j = 0; j < 8; j++)
                acc[i][j] = __builtin_amdgcn_mfma_f32_16x16x32_bf16(af[i], bf[j], acc[i][j], 0, 0, 0);

        if (t + 3 < NT)      asm volatile("s_waitcnt vmcnt(8)" ::: "memory");  // t+1 landed
        else if (t + 2 < NT) asm volatile("s_waitcnt vmcnt(4)" ::: "memory");
        else if (t + 1 < NT) asm volatile("s_waitcnt vmcnt(0)" ::: "memory");
        if (t + 1 < NT) {
            __builtin_amdgcn_s_barrier();
            asm volatile("" ::: "memory");
        }
    }

    // ---- epilogue ----
    if (tn < 20) {   // Q or K: bias + RoPE + head-major write
        const int qk = (tn < 16);
        const int hd = qk ? tn : (tn - 16);
        u16* base = qk ? (Qr + (size_t)hd * 2048 * 128) : (Kr + (size_t)hd * 2048 * 128);
        float bia0[4], bia1[4], inv[4];
#pragma unroll
        for (int j = 0; j < 4; j++) {
            const int ip = j * 16 + l16;
            bia0[j] = bias[tn * 128 + ip];
            bia1[j] = bias[tn * 128 + ip + 64];
            inv[j] = exp2f(-(float)ip * L2T);
        }
#pragma unroll
        for (int i = 0; i < 2; i++) {
            const int s0 = tm * 128 + w * 32 + i * 16 + quad * 4;
#pragma unroll
            for (int r = 0; r < 4; r++) {
                const int s = s0 + r;
                const float fs = (float)s;
                u16* rowp = base + (size_t)s * 128;
#pragma unroll
                for (int j = 0; j < 4; j++) {
                    const int ip = j * 16 + l16;
                    float sn, cs;
                    __sincosf(fs * inv[j], &sn, &cs);
                    const float a0 = acc[i][j][r] + bia0[j];
                    const float a1 = acc[i][j + 4][r] + bia1[j];
                    rowp[ip]      = f2bf(a0 * cs - a1 * sn);
                    rowp[ip + 64] = f2bf(a1 * cs + a0 * sn);
                }
            }
        }
    } else {         // V: bias + transposed write to Vt[4][128][2048]
        const int kvh = tn - 20;
#pragma unroll
        for (int j = 0; j < 8; j++) {
            const int d = j * 16 + l16;
            const float bv = bias[tn * 128 + d];
            u16* base = Vt + ((size_t)(kvh * 128 + d)) * 2048;
#pragma unroll
            for (int i = 0; i < 2; i++) {
                const int s0 = tm * 128 + w * 32 + i * 16 + quad * 4;
                u16x4 o;
#pragma unroll
                for (int r = 0; r < 4; r++) o[r] = f2bf(acc[i][j][r] + bv);
                *(u16x4*)(base + s0) = o;
            }
        }
    }
}

// ---------------- GEMM: C[M][N] = A[M][K](bf16) * B[N][K]^T(bf16), fp32 out ----------------
// 128x128 tile, BK=32, 256 threads = 4 waves (2x2), m97 structure + depth-3 counted-vmcnt
// pipeline (see gemm_qkv_rope comment).
__global__ __launch_bounds__(256) void gemm_bt(const u16* __restrict__ A, const u16* __restrict__ B,
                                               float* __restrict__ C, int M, int N, int K) {
    __shared__ u16 As[4][128 * 32];
    __shared__ u16 Bs[4][128 * 32];
    const int tm = blockIdx.y, tn = blockIdx.x;
    const int tid = threadIdx.x;
    const int w = tid >> 6, lane = tid & 63, quad = lane >> 4, l16 = lane & 15;
    const int wm = w >> 1, wn = w & 1;
    const int NT = K >> 5;

    f4 acc[4][4];
#pragma unroll
    for (int i = 0; i < 4; i++)
#pragma unroll
        for (int j = 0; j < 4; j++) acc[i][j] = f4{0.f, 0.f, 0.f, 0.f};

    const int srow = w * 32 + (lane >> 2);
    const int scol = (lane & 3) * 8;
    const u16* aPtr = A + (size_t)(tm * 128 + srow) * K + scol;
    const u16* bPtr = B + (size_t)(tn * 128 + srow) * K + scol;
    const size_t rowskip = (size_t)16 * K;

    auto stage = [&](int buf, int kk) {
        gload16(aPtr + kk,           &As[buf][(w * 32) * 32]);
        gload16(aPtr + kk + rowskip, &As[buf][(w * 32 + 16) * 32]);
        gload16(bPtr + kk,           &Bs[buf][(w * 32) * 32]);
        gload16(bPtr + kk + rowskip, &Bs[buf][(w * 32 + 16) * 32]);
    };

    stage(0, 0); stage(1, 32); stage(2, 64);
    asm volatile("s_waitcnt vmcnt(8)" ::: "memory");   // tile 0 landed; 1,2 in flight
    __builtin_amdgcn_s_barrier();
    asm volatile("" ::: "memory");

    for (int t = 0; t < NT; t++) {
        const int cur = t & 3;
        if (t + 3 < NT) stage((t + 3) & 3, (t + 3) * 32);

        bfrag af[4], bf[4];
#pragma unroll
        for (int i = 0; i < 4; i++)
            af[i] = *(const bfrag*)(&As[cur][(wm * 64 + i * 16 + l16) * 32 + quad * 8]);
#pragma unroll
        for (int j = 0; j < 4; j++)
            bf[j] = *(const bfrag*)(&Bs[cur][(wn * 64 + j * 16 + l16) * 32 + quad * 8]);
#pragma unroll
        for (int i = 0; i < 4; i++)
#pragma unroll
            for (int j = 0; j < 4; j++)
                acc[i][j] = __builtin_amdgcn_mfma_f32_16x16x32_bf16(af[i], bf[j], acc[i][j], 0, 0, 0);

        if (t + 3 < NT)      asm volatile("s_waitcnt vmcnt(8)" ::: "memory");  // t+1 landed
        else if (t + 2 < NT) asm volatile("s_waitcnt vmcnt(4)" ::: "memory");
        else if (t + 1 < NT) asm volatile("s_waitcnt vmcnt(0)" ::: "memory");
        if (t + 1 < NT) {
            __builtin_amdgcn_s_barrier();
            asm volatile("" ::: "memory");
        }
    }

#pragma unroll
    for (int i = 0; i < 4; i++) {
#pragma unroll
        for (int j = 0; j < 4; j++) {
            const int col = tn * 128 + wn * 64 + j * 16 + l16;
#pragma unroll
            for (int r = 0; r < 4; r++) {
                const int row = tm * 128 + wm * 64 + i * 16 + quad * 4 + r;
                C[(size_t)row * N + col] = acc[i][j][r];
            }
        }
    }
}

// ---------------- flash attention (causal), S^T formulation, 128-key tiles ----------------
// [round-0 kernel, measured 64.1 us -- best of 6 variants; rounds 1-5 all regressed]
// 512 blocks x 256 threads = 4 waves. Block = (kv head, 16-row q-group g); wave w = q-head
// kv*4+w on the same 16 rows (GQA-shared staging). S^T via swapped-operand 16x16x32 MFMA:
// D[key][q] -> lane holds P[q=l16][key=quad*4+r], which IS the 16x16x16 MFMA operand layout,
// so PV runs as mfma_f32_16x16x16bf16_1k with NO P LDS round-trip and no in-loop shuffles.
// O accumulated as O[q=l16][d=ct*16+quad*4+r] (C-layout of A=V^T, B=P). Streaming softmax.
__global__ __launch_bounds__(256) void flash_attn(const u16* __restrict__ Qr, const u16* __restrict__ Kr,
                                                  const u16* __restrict__ Vt, u16* __restrict__ attnout) {
    const int bid = blockIdx.x;
    const int kv = bid & 3;
    const int gy = bid >> 2;          // 0..127
    const int g = ((gy & 1) << 6) | ((gy & 2) << 4) | ((gy & 4) << 2) | (gy & 8) |
                  ((gy & 16) >> 2) | ((gy & 32) >> 4) | ((gy & 64) >> 6);   // bitrev7
    const int tid = threadIdx.x;
    const int w = tid >> 6, lane = tid & 63, quad = lane >> 4, l16 = lane & 15;
    const int h = kv * 4 + w;         // wave's q-head

    __shared__ u16 ks[128 * 128];     // K tile [128 keys][128 d], swizzled 16B chunks
    __shared__ u16 vt[128 * 128];     // V^T tile [128 d][128 keys], swizzled 16B chunks

    // Q fragments (B-operand layout: rows q=l16, k at quad*8)
    bfrag aq[4];
    const u16* qbase = Qr + ((size_t)(h * 2048 + g * 16 + l16)) * 128 + quad * 8;
#pragma unroll
    for (int kb = 0; kb < 4; kb++) aq[kb] = *(const bfrag*)(qbase + kb * 32);

    f4 oacc[8];
#pragma unroll
    for (int ct = 0; ct < 8; ct++) oacc[ct] = f4{0.f, 0.f, 0.f, 0.f};
    float psum = 0.f;                 // per-lane partial row-sum for q = l16

    const int qg = g * 16 + l16;      // this lane's global q row
    const int ktn = g / 8 + 1;        // 128-key tiles for rows [g*16, g*16+16)
    const float C = 0.08838834764831845f * 1.4426950408889634f;  // (1/sqrt(128))*log2(e)
    const u16* kbase = Kr + (size_t)kv * 2048 * 128;
    const u16* vbase = Vt + (size_t)kv * 128 * 2048;

    for (int kt = 0; kt < ktn; kt++) {
        __syncthreads();
        // stage K [128][128]: 2048 chunks of 16B, 8 per thread
#pragma unroll
        for (int i = 0; i < 8; i++) {
            const int ci = (w * 8 + i) * 64 + lane;
            const int r = ci >> 4, c = (ci & 15) ^ (r & 15);
            gload16(kbase + (size_t)(kt * 128 + r) * 128 + c * 8, &ks[(w * 8 + i) * 512]);
        }
        // stage V^T [128 d][128 keys]: 2048 chunks
#pragma unroll
        for (int i = 0; i < 8; i++) {
            const int ci = (w * 8 + i) * 64 + lane;
            const int r = ci >> 4, c = (ci & 15) ^ (r & 15);
            gload16(vbase + (size_t)r * 2048 + kt * 128 + c * 8, &vt[(w * 8 + i) * 512]);
        }
        __syncthreads();

        // S^T: D[key][q] over 128 keys; A = K-frag (rows key), B = aq
        f4 sc[8];
#pragma unroll
        for (int nt = 0; nt < 8; nt++) {
            f4 c = f4{0.f, 0.f, 0.f, 0.f};
#pragma unroll
            for (int kb = 0; kb < 4; kb++) {
                bfrag a = *(const bfrag*)(&ks[((nt * 16 + l16) * 16 + ((quad + kb * 4) ^ l16)) * 8]);
                c = __builtin_amdgcn_mfma_f32_16x16x32_bf16(a, aq[kb], c, 0, 0, 0);
            }
            sc[nt] = c;
        }

        if (kt == ktn - 1) {          // only the last tile needs causal masking
#pragma unroll
            for (int nt = 0; nt < 8; nt++) {
                const int key = kt * 128 + nt * 16 + quad * 4;
#pragma unroll
                for (int r = 0; r < 4; r++)
                    if (key + r > qg) sc[nt][r] = -INFINITY;
            }
        }

        // streaming softmax + in-lane P pack (A/B-operand layout for 16x16x16)
        s4 pa[8];
#pragma unroll
        for (int nt = 0; nt < 8; nt++) {
#pragma unroll
            for (int r = 0; r < 4; r++) {
                const float p = exp2f(fminf(sc[nt][r] * C, 40.f));
                psum += p;
                pa[nt][r] = (short)f2bf(p);
            }
        }

        // O[q][d] += P*V via 16x16x16: A = V^T frag (rows d), B = P
#pragma unroll
        for (int nt = 0; nt < 8; nt++) {
#pragma unroll
            for (int ct = 0; ct < 8; ct++) {
                const int d = ct * 16 + l16;
                s4 a = *(const s4*)(&vt[(d * 16 + ((nt * 2 + (quad >> 1)) ^ l16)) * 8 + (quad & 1) * 4]);
                oacc[ct] = __builtin_amdgcn_mfma_f32_16x16x16bf16_1k(a, pa[nt], oacc[ct], 0, 0, 0);
            }
        }
    }

    // epilogue: reduce psum over the 4 quads sharing q=l16, normalize, vector-store
    float s = psum;
    s += __shfl_xor(s, 16, 64);
    s += __shfl_xor(s, 32, 64);
    const float inv_l = 1.0f / s;
    u16* orow = attnout + (size_t)qg * 2048 + h * 128;
#pragma unroll
    for (int ct = 0; ct < 8; ct++) {
        u16x4 o;
#pragma unroll
        for (int r = 0; r < 4; r++) o[r] = f2bf(oacc[ct][r] * inv_l);
        *(u16x4*)(orow + ct * 16 + quad * 4) = o;
    }
}

// ---------------- launch ----------------
extern "C" void kernel_launch(void* const* d_in, const int* in_sizes, int n_in,
                              void* d_out, int out_size, void* d_ws, size_t ws_size,
                              hipStream_t stream) {
    const float* X  = (const float*)d_in[0];
    const float* wq = (const float*)d_in[3];
    const float* bq = (const float*)d_in[4];
    const float* wk = (const float*)d_in[5];
    const float* bk = (const float*)d_in[6];
    const float* wv = (const float*)d_in[7];
    const float* bv = (const float*)d_in[8];
    const float* wo = (const float*)d_in[9];

    char* ws = (char*)d_ws;
    u16*   Xb      = (u16*)(ws);                         // 8 MB
    u16*   Wqkv    = (u16*)(ws + 8388608);               // 12 MB  [3072][2048]
    u16*   Wo      = (u16*)(ws + 20971520);              // 8 MB
    float* biasqkv = (float*)(ws + 29360128);            // 12 KB
    u16*   Qr      = (u16*)(ws + 54538240);              // 8 MB   [16][2048][128]
    u16*   Kr      = (u16*)(ws + 62926848);              // 2 MB   [4][2048][128]
    u16*   attnout = (u16*)(ws + 67121152);              // 8 MB   [2048][2048]
    u16*   Vt      = (u16*)(ws + 75509760);              // 2 MB   [4][128][2048]

    prep<<<14339, 256, 0, stream>>>(X, wq, wk, wv, wo, bq, bk, bv, Xb, Wqkv, Wo, biasqkv);
    gemm_qkv_rope<<<dim3(24, 16), 256, 0, stream>>>(Xb, Wqkv, biasqkv, Qr, Kr, Vt);
    flash_attn<<<512, 256, 0, stream>>>(Qr, Kr, Vt, attnout);
    gemm_bt<<<dim3(16, 16), 256, 0, stream>>>(attnout, Wo, (float*)d_out, 2048, 2048, 2048);
}

// Round 8
// 259.607 us; speedup vs baseline: 1.2519x; 1.0381x over previous
//
#include <hip/hip_runtime.h>

typedef __attribute__((ext_vector_type(8))) short bfrag;   // 8 bf16 (4 VGPRs) MFMA operand
typedef __attribute__((ext_vector_type(4))) short s4;      // 4 bf16 (2 VGPRs) 16x16x16 operand
typedef __attribute__((ext_vector_type(4))) float f4;      // MFMA accumulator
typedef unsigned short u16;
typedef __attribute__((ext_vector_type(4))) unsigned short u16x4;

#define L2T 0.20762050593046f   // log2(10000)/64

__device__ inline u16 f2bf(float x) {
    unsigned u = __builtin_bit_cast(unsigned, x);
    u += 0x7FFFu + ((u >> 16) & 1u);   // round-to-nearest-even
    return (u16)(u >> 16);
}

__device__ inline void gload16(const u16* g, u16* l) {
    // async global->LDS, 16B/lane; LDS dst = wave-uniform base + lane*16
    __builtin_amdgcn_global_load_lds((const __attribute__((address_space(1))) u16*)g,
                                     (__attribute__((address_space(3))) u16*)l, 16, 0, 0);
}

// ---------------- fused prep: cast X/wq/wk/wv/wo -> bf16, concat biases ----------------
__global__ __launch_bounds__(256) void prep(const float* __restrict__ X,  const float* __restrict__ wq,
                                            const float* __restrict__ wk, const float* __restrict__ wv,
                                            const float* __restrict__ wo, const float* __restrict__ bq,
                                            const float* __restrict__ bk, const float* __restrict__ bv,
                                            u16* __restrict__ Xb, u16* __restrict__ Wqkv,
                                            u16* __restrict__ Wo_, float* __restrict__ biasqkv) {
    const int v = blockIdx.x * 256 + threadIdx.x;
    const float* src; u16* dst; int idx;
    if (v < 1048576)      { src = X;  dst = Xb;              idx = v; }
    else if (v < 2097152) { src = wq; dst = Wqkv;            idx = v - 1048576; }
    else if (v < 2359296) { src = wk; dst = Wqkv + 4194304;  idx = v - 2097152; }
    else if (v < 2621440) { src = wv; dst = Wqkv + 5242880;  idx = v - 2359296; }
    else if (v < 3670016) { src = wo; dst = Wo_;             idx = v - 2621440; }
    else {
        const int b = v - 3670016;   // 768 float4 = 3072 bias floats
        const float* s = (b < 512) ? (bq + b * 4) : (b < 640) ? (bk + (b - 512) * 4) : (bv + (b - 640) * 4);
        *(float4*)(biasqkv + b * 4) = *(const float4*)s;
        return;
    }
    float4 t = *(const float4*)(src + (size_t)idx * 4);
    u16x4 o;
    o.x = f2bf(t.x); o.y = f2bf(t.y); o.z = f2bf(t.z); o.w = f2bf(t.w);
    *(u16x4*)(dst + (size_t)idx * 4) = o;
}

// ---------------- fused QKV GEMM + bias + RoPE + repack ----------------
// C = Xb[2048][2048] * Wqkv[3072][2048]^T. 64x128 tiles (M-halved vs m97's 128x128) ->
// grid 24x32 = 768 blocks = 3 blocks/CU co-resident (LDS 48KB x3 = 144 <= 160KB).
// Rationale: m102's shape curve shows the SAME kernel at 1 block/CU = 320 TF vs 4/CU =
// 833 TF -- co-residency, not per-block schedule, is the N=2048 lever (depth-3 vmcnt was
// neutral at 1 block/CU, round 7). 4 waves; wave w owns rows w*16..+15 x all 128 cols
// (acc[8]) so RoPE partners (ip, ip+64) stay acc[j] <-> acc[j+4] IN-LANE.
// tn: 0..15 Q head tn, 16..19 K head tn-16, 20..23 V kv-head tn-20 (transposed to Vt).
// Depth-3 counted-vmcnt pipeline kept: 3 loads/stage -> steady vmcnt(6), tail 3 -> 0.
__global__ __launch_bounds__(256) void gemm_qkv_rope(const u16* __restrict__ A, const u16* __restrict__ B,
                                                     const float* __restrict__ bias,
                                                     u16* __restrict__ Qr, u16* __restrict__ Kr,
                                                     u16* __restrict__ Vt) {
    const int K = 2048;
    const int NT = 64;                 // K/32
    __shared__ u16 As[4][64 * 32];     // 16 KB
    __shared__ u16 Bs[4][128 * 32];    // 32 KB
    const int tm = blockIdx.y, tn = blockIdx.x;
    const int tid = threadIdx.x;
    const int w = tid >> 6, lane = tid & 63, quad = lane >> 4, l16 = lane & 15;

    f4 acc[8];
#pragma unroll
    for (int j = 0; j < 8; j++) acc[j] = f4{0.f, 0.f, 0.f, 0.f};

    // staging: A tile 64x32 (1 gload16/thread), B tile 128x32 (2 gload16/thread)
    const u16* aPtr = A + (size_t)(tm * 64 + w * 16 + (lane >> 2)) * K + (lane & 3) * 8;
    const u16* bPtr = B + (size_t)(tn * 128 + w * 32 + (lane >> 2)) * K + (lane & 3) * 8;
    const size_t rowskip = (size_t)16 * K;

    auto stage = [&](int buf, int kk) {
        gload16(aPtr + kk,           &As[buf][(w * 16) * 32]);
        gload16(bPtr + kk,           &Bs[buf][(w * 32) * 32]);
        gload16(bPtr + kk + rowskip, &Bs[buf][(w * 32 + 16) * 32]);
    };

    stage(0, 0); stage(1, 32); stage(2, 64);
    asm volatile("s_waitcnt vmcnt(6)" ::: "memory");   // tile 0 landed; 1,2 in flight
    __builtin_amdgcn_s_barrier();
    asm volatile("" ::: "memory");

    for (int t = 0; t < NT; t++) {
        const int cur = t & 3;
        if (t + 3 < NT) stage((t + 3) & 3, (t + 3) * 32);

        bfrag af, bf[8];
        af = *(const bfrag*)(&As[cur][(w * 16 + l16) * 32 + quad * 8]);
#pragma unroll
        for (int j = 0; j < 8; j++)
            bf[j] = *(const bfrag*)(&Bs[cur][(j * 16 + l16) * 32 + quad * 8]);
#pragma unroll
        for (int j = 0; j < 8; j++)
            acc[j] = __builtin_amdgcn_mfma_f32_16x16x32_bf16(af, bf[j], acc[j], 0, 0, 0);

        if (t + 3 < NT)      asm volatile("s_waitcnt vmcnt(6)" ::: "memory");  // t+1 landed
        else if (t + 2 < NT) asm volatile("s_waitcnt vmcnt(3)" ::: "memory");
        else if (t + 1 < NT) asm volatile("s_waitcnt vmcnt(0)" ::: "memory");
        if (t + 1 < NT) {
            __builtin_amdgcn_s_barrier();
            asm volatile("" ::: "memory");
        }
    }

    // ---- epilogue ----
    if (tn < 20) {   // Q or K: bias + RoPE + head-major write
        const int qk = (tn < 16);
        const int hd = qk ? tn : (tn - 16);
        u16* base = qk ? (Qr + (size_t)hd * 2048 * 128) : (Kr + (size_t)hd * 2048 * 128);
        float bia0[4], bia1[4], inv[4];
#pragma unroll
        for (int j = 0; j < 4; j++) {
            const int ip = j * 16 + l16;
            bia0[j] = bias[tn * 128 + ip];
            bia1[j] = bias[tn * 128 + ip + 64];
            inv[j] = exp2f(-(float)ip * L2T);
        }
        const int s0 = tm * 64 + w * 16 + quad * 4;
#pragma unroll
        for (int r = 0; r < 4; r++) {
            const int s = s0 + r;
            const float fs = (float)s;
            u16* rowp = base + (size_t)s * 128;
#pragma unroll
            for (int j = 0; j < 4; j++) {
                const int ip = j * 16 + l16;
                float sn, cs;
                __sincosf(fs * inv[j], &sn, &cs);
                const float a0 = acc[j][r] + bia0[j];
                const float a1 = acc[j + 4][r] + bia1[j];
                rowp[ip]      = f2bf(a0 * cs - a1 * sn);
                rowp[ip + 64] = f2bf(a1 * cs + a0 * sn);
            }
        }
    } else {         // V: bias + transposed write to Vt[4][128][2048]
        const int kvh = tn - 20;
        const int s0 = tm * 64 + w * 16 + quad * 4;
#pragma unroll
        for (int j = 0; j < 8; j++) {
            const int d = j * 16 + l16;
            const float bv = bias[tn * 128 + d];
            u16* base = Vt + ((size_t)(kvh * 128 + d)) * 2048;
            u16x4 o;
#pragma unroll
            for (int r = 0; r < 4; r++) o[r] = f2bf(acc[j][r] + bv);
            *(u16x4*)(base + s0) = o;
        }
    }
}

// ---------------- GEMM: C[M][N] = A[M][K](bf16) * B[N][K]^T(bf16), fp32 out ----------------
// 64x128 tile -> grid 16x32 = 512 blocks = 2 blocks/CU co-resident (see gemm_qkv_rope
// comment: co-residency is the N=2048 lever). 4 waves; wave w owns rows w*16..+15 x all
// 128 cols (acc[8]). Depth-3 counted-vmcnt pipeline, 3 loads/stage.
__global__ __launch_bounds__(256) void gemm_bt(const u16* __restrict__ A, const u16* __restrict__ B,
                                               float* __restrict__ C, int M, int N, int K) {
    __shared__ u16 As[4][64 * 32];     // 16 KB
    __shared__ u16 Bs[4][128 * 32];    // 32 KB
    const int tm = blockIdx.y, tn = blockIdx.x;
    const int tid = threadIdx.x;
    const int w = tid >> 6, lane = tid & 63, quad = lane >> 4, l16 = lane & 15;
    const int NT = K >> 5;

    f4 acc[8];
#pragma unroll
    for (int j = 0; j < 8; j++) acc[j] = f4{0.f, 0.f, 0.f, 0.f};

    const u16* aPtr = A + (size_t)(tm * 64 + w * 16 + (lane >> 2)) * K + (lane & 3) * 8;
    const u16* bPtr = B + (size_t)(tn * 128 + w * 32 + (lane >> 2)) * K + (lane & 3) * 8;
    const size_t rowskip = (size_t)16 * K;

    auto stage = [&](int buf, int kk) {
        gload16(aPtr + kk,           &As[buf][(w * 16) * 32]);
        gload16(bPtr + kk,           &Bs[buf][(w * 32) * 32]);
        gload16(bPtr + kk + rowskip, &Bs[buf][(w * 32 + 16) * 32]);
    };

    stage(0, 0); stage(1, 32); stage(2, 64);
    asm volatile("s_waitcnt vmcnt(6)" ::: "memory");   // tile 0 landed; 1,2 in flight
    __builtin_amdgcn_s_barrier();
    asm volatile("" ::: "memory");

    for (int t = 0; t < NT; t++) {
        const int cur = t & 3;
        if (t + 3 < NT) stage((t + 3) & 3, (t + 3) * 32);

        bfrag af, bf[8];
        af = *(const bfrag*)(&As[cur][(w * 16 + l16) * 32 + quad * 8]);
#pragma unroll
        for (int j = 0; j < 8; j++)
            bf[j] = *(const bfrag*)(&Bs[cur][(j * 16 + l16) * 32 + quad * 8]);
#pragma unroll
        for (int j = 0; j < 8; j++)
            acc[j] = __builtin_amdgcn_mfma_f32_16x16x32_bf16(af, bf[j], acc[j], 0, 0, 0);

        if (t + 3 < NT)      asm volatile("s_waitcnt vmcnt(6)" ::: "memory");  // t+1 landed
        else if (t + 2 < NT) asm volatile("s_waitcnt vmcnt(3)" ::: "memory");
        else if (t + 1 < NT) asm volatile("s_waitcnt vmcnt(0)" ::: "memory");
        if (t + 1 < NT) {
            __builtin_amdgcn_s_barrier();
            asm volatile("" ::: "memory");
        }
    }

#pragma unroll
    for (int j = 0; j < 8; j++) {
        const int col = tn * 128 + j * 16 + l16;
#pragma unroll
        for (int r = 0; r < 4; r++) {
            const int row = tm * 64 + w * 16 + quad * 4 + r;
            C[(size_t)row * N + col] = acc[j][r];
        }
    }
}

// ---------------- flash attention (causal), S^T formulation, 128-key tiles ----------------
// [round-0 kernel, measured 64.1 us -- best of 6 variants; rounds 1-5 all regressed]
// 512 blocks x 256 threads = 4 waves. Block = (kv head, 16-row q-group g); wave w = q-head
// kv*4+w on the same 16 rows (GQA-shared staging). S^T via swapped-operand 16x16x32 MFMA:
// D[key][q] -> lane holds P[q=l16][key=quad*4+r], which IS the 16x16x16 MFMA operand layout,
// so PV runs as mfma_f32_16x16x16bf16_1k with NO P LDS round-trip and no in-loop shuffles.
// O accumulated as O[q=l16][d=ct*16+quad*4+r] (C-layout of A=V^T, B=P). Streaming softmax.
__global__ __launch_bounds__(256) void flash_attn(const u16* __restrict__ Qr, const u16* __restrict__ Kr,
                                                  const u16* __restrict__ Vt, u16* __restrict__ attnout) {
    const int bid = blockIdx.x;
    const int kv = bid & 3;
    const int gy = bid >> 2;          // 0..127
    const int g = ((gy & 1) << 6) | ((gy & 2) << 4) | ((gy & 4) << 2) | (gy & 8) |
                  ((gy & 16) >> 2) | ((gy & 32) >> 4) | ((gy & 64) >> 6);   // bitrev7
    const int tid = threadIdx.x;
    const int w = tid >> 6, lane = tid & 63, quad = lane >> 4, l16 = lane & 15;
    const int h = kv * 4 + w;         // wave's q-head

    __shared__ u16 ks[128 * 128];     // K tile [128 keys][128 d], swizzled 16B chunks
    __shared__ u16 vt[128 * 128];     // V^T tile [128 d][128 keys], swizzled 16B chunks

    // Q fragments (B-operand layout: rows q=l16, k at quad*8)
    bfrag aq[4];
    const u16* qbase = Qr + ((size_t)(h * 2048 + g * 16 + l16)) * 128 + quad * 8;
#pragma unroll
    for (int kb = 0; kb < 4; kb++) aq[kb] = *(const bfrag*)(qbase + kb * 32);

    f4 oacc[8];
#pragma unroll
    for (int ct = 0; ct < 8; ct++) oacc[ct] = f4{0.f, 0.f, 0.f, 0.f};
    float psum = 0.f;                 // per-lane partial row-sum for q = l16

    const int qg = g * 16 + l16;      // this lane's global q row
    const int ktn = g / 8 + 1;        // 128-key tiles for rows [g*16, g*16+16)
    const float C = 0.08838834764831845f * 1.4426950408889634f;  // (1/sqrt(128))*log2(e)
    const u16* kbase = Kr + (size_t)kv * 2048 * 128;
    const u16* vbase = Vt + (size_t)kv * 128 * 2048;

    for (int kt = 0; kt < ktn; kt++) {
        __syncthreads();
        // stage K [128][128]: 2048 chunks of 16B, 8 per thread
#pragma unroll
        for (int i = 0; i < 8; i++) {
            const int ci = (w * 8 + i) * 64 + lane;
            const int r = ci >> 4, c = (ci & 15) ^ (r & 15);
            gload16(kbase + (size_t)(kt * 128 + r) * 128 + c * 8, &ks[(w * 8 + i) * 512]);
        }
        // stage V^T [128 d][128 keys]: 2048 chunks
#pragma unroll
        for (int i = 0; i < 8; i++) {
            const int ci = (w * 8 + i) * 64 + lane;
            const int r = ci >> 4, c = (ci & 15) ^ (r & 15);
            gload16(vbase + (size_t)r * 2048 + kt * 128 + c * 8, &vt[(w * 8 + i) * 512]);
        }
        __syncthreads();

        // S^T: D[key][q] over 128 keys; A = K-frag (rows key), B = aq
        f4 sc[8];
#pragma unroll
        for (int nt = 0; nt < 8; nt++) {
            f4 c = f4{0.f, 0.f, 0.f, 0.f};
#pragma unroll
            for (int kb = 0; kb < 4; kb++) {
                bfrag a = *(const bfrag*)(&ks[((nt * 16 + l16) * 16 + ((quad + kb * 4) ^ l16)) * 8]);
                c = __builtin_amdgcn_mfma_f32_16x16x32_bf16(a, aq[kb], c, 0, 0, 0);
            }
            sc[nt] = c;
        }

        if (kt == ktn - 1) {          // only the last tile needs causal masking
#pragma unroll
            for (int nt = 0; nt < 8; nt++) {
                const int key = kt * 128 + nt * 16 + quad * 4;
#pragma unroll
                for (int r = 0; r < 4; r++)
                    if (key + r > qg) sc[nt][r] = -INFINITY;
            }
        }

        // streaming softmax + in-lane P pack (A/B-operand layout for 16x16x16)
        s4 pa[8];
#pragma unroll
        for (int nt = 0; nt < 8; nt++) {
#pragma unroll
            for (int r = 0; r < 4; r++) {
                const float p = exp2f(fminf(sc[nt][r] * C, 40.f));
                psum += p;
                pa[nt][r] = (short)f2bf(p);
            }
        }

        // O[q][d] += P*V via 16x16x16: A = V^T frag (rows d), B = P
#pragma unroll
        for (int nt = 0; nt < 8; nt++) {
#pragma unroll
            for (int ct = 0; ct < 8; ct++) {
                const int d = ct * 16 + l16;
                s4 a = *(const s4*)(&vt[(d * 16 + ((nt * 2 + (quad >> 1)) ^ l16)) * 8 + (quad & 1) * 4]);
                oacc[ct] = __builtin_amdgcn_mfma_f32_16x16x16bf16_1k(a, pa[nt], oacc[ct], 0, 0, 0);
            }
        }
    }

    // epilogue: reduce psum over the 4 quads sharing q=l16, normalize, vector-store
    float s = psum;
    s += __shfl_xor(s, 16, 64);
    s += __shfl_xor(s, 32, 64);
    const float inv_l = 1.0f / s;
    u16* orow = attnout + (size_t)qg * 2048 + h * 128;
#pragma unroll
    for (int ct = 0; ct < 8; ct++) {
        u16x4 o;
#pragma unroll
        for (int r = 0; r < 4; r++) o[r] = f2bf(oacc[ct][r] * inv_l);
        *(u16x4*)(orow + ct * 16 + quad * 4) = o;
    }
}

// ---------------- launch ----------------
extern "C" void kernel_launch(void* const* d_in, const int* in_sizes, int n_in,
                              void* d_out, int out_size, void* d_ws, size_t ws_size,
                              hipStream_t stream) {
    const float* X  = (const float*)d_in[0];
    const float* wq = (const float*)d_in[3];
    const float* bq = (const float*)d_in[4];
    const float* wk = (const float*)d_in[5];
    const float* bk = (const float*)d_in[6];
    const float* wv = (const float*)d_in[7];
    const float* bv = (const float*)d_in[8];
    const float* wo = (const float*)d_in[9];

    char* ws = (char*)d_ws;
    u16*   Xb      = (u16*)(ws);                         // 8 MB
    u16*   Wqkv    = (u16*)(ws + 8388608);               // 12 MB  [3072][2048]
    u16*   Wo      = (u16*)(ws + 20971520);              // 8 MB
    float* biasqkv = (float*)(ws + 29360128);            // 12 KB
    u16*   Qr      = (u16*)(ws + 54538240);              // 8 MB   [16][2048][128]
    u16*   Kr      = (u16*)(ws + 62926848);              // 2 MB   [4][2048][128]
    u16*   attnout = (u16*)(ws + 67121152);              // 8 MB   [2048][2048]
    u16*   Vt      = (u16*)(ws + 75509760);              // 2 MB   [4][128][2048]

    prep<<<14339, 256, 0, stream>>>(X, wq, wk, wv, wo, bq, bk, bv, Xb, Wqkv, Wo, biasqkv);
    gemm_qkv_rope<<<dim3(24, 32), 256, 0, stream>>>(Xb, Wqkv, biasqkv, Qr, Kr, Vt);
    flash_attn<<<512, 256, 0, stream>>>(Qr, Kr, Vt, attnout);
    gemm_bt<<<dim3(16, 32), 256, 0, stream>>>(attnout, Wo, (float*)d_out, 2048, 2048, 2048);
}